// Round 11
// baseline (287.285 us; speedup 1.0000x reference)
//
#include <hip/hip_runtime.h>

#define BATCH 8
#define NCLS  19
#define LOGN  18
#define NPIX  (1u << LOGN)      // 262144 pixels per image
#define NB    64                // histogram bins over p in [0,1)
#define BLK1  512
#define BPB   64                // blocks per image (R4 champion config)
#define HCOPY 8                 // LDS histogram copies (lane & 7)
#define HSTR  (NCLS * NB + 4)   // 1220 words; copies start on distinct banks

// ---------------- Kernel 1 (R4 champion body), templated for phase ablation.
// VARIANT 0: full.  1: loads+exp+sum+rcp only.  2: +bin/ps VALU, no DS atomics.
// 3: full minus ps accumulation.  NPASS=3 for probes (to enter rocprof top-5).
template<int VARIANT, int NPASS>
__global__ __launch_bounds__(BLK1, 4) void k_hist(
    const float* __restrict__ pred, const int* __restrict__ target,
    unsigned short* __restrict__ hist_part, float* __restrict__ s2_part)
{
    __shared__ unsigned hist[HCOPY * HSTR];       // 39040 B
    __shared__ float    s2w[BLK1 / 64][NCLS];

    const int b     = blockIdx.x / BPB;
    const int chunk = blockIdx.x % BPB;
    const int tid   = threadIdx.x;
    const int lane  = tid & 63;
    const int wid   = tid >> 6;

    unsigned* hpar = hist + (lane & (HCOPY - 1)) * HSTR;

    for (int i = tid; i < HCOPY * HSTR; i += BLK1) hist[i] = 0u;
    __syncthreads();

    float ps[NCLS];
    #pragma unroll
    for (int c = 0; c < NCLS; ++c) ps[c] = 0.0f;

    const float* pb   = pred + (((size_t)b * NCLS) << LOGN);
    const int*   tb   = target + ((size_t)b << LOGN);
    const int    base = chunk * (int)(NPIX / BPB);

    #pragma unroll 1
    for (int pass = 0; pass < NPASS; ++pass) {
        #pragma unroll 1
        for (int it = 0; it < (int)(NPIX / BPB) / (2 * BLK1); ++it) {   // 4 iters
            const int n = base + it * (2 * BLK1) + 2 * tid;

            const int2 tg = *reinterpret_cast<const int2*>(tb + n);

            float2 e2[NCLS];
            float sA = 0.0f, sB = 0.0f;
            #pragma unroll
            for (int c = 0; c < NCLS; ++c) {
                const float2 x = *reinterpret_cast<const float2*>(pb + (((size_t)c) << LOGN) + n);
                const float eA = __expf(x.x);
                const float eB = __expf(x.y);
                e2[c].x = eA; e2[c].y = eB;
                sA += eA; sB += eB;
            }
            const float rA = __builtin_amdgcn_rcpf(sA) * (float)NB;   // p*NB scale
            const float rB = __builtin_amdgcn_rcpf(sB) * (float)NB;

            if constexpr (VARIANT == 1) {
                // keep the load+exp+sum+rcp chain and tg live (rule #17)
                asm volatile("" :: "v"(rA), "v"(rB), "v"(tg.x), "v"(tg.y));
            } else {
                #pragma unroll
                for (int c = 0; c < NCLS; ++c) {
                    const float tA = e2[c].x * rA;
                    const float tB = e2[c].y * rB;
                    int binA = (int)tA; binA = binA > NB - 1 ? NB - 1 : binA;
                    int binB = (int)tB; binB = binB > NB - 1 ? NB - 1 : binB;
                    if constexpr (VARIANT != 3) {
                        ps[c] += ((c == tg.x) ? fmaf(tA, -1.0f / (float)NB, 1.0f) : 0.0f)
                               + ((c == tg.y) ? fmaf(tB, -1.0f / (float)NB, 1.0f) : 0.0f);
                    }
                    if constexpr (VARIANT == 2) {
                        asm volatile("" :: "v"(binA), "v"(binB));   // keep bin calc live
                    } else {
                        if (c != tg.x) atomicAdd(&hpar[c * NB + binA], 1u);
                        if (c != tg.y) atomicAdd(&hpar[c * NB + binB], 1u);
                    }
                }
            }
        }
    }
    __syncthreads();

    // s2: wave shuffle-reduce, then cross-wave via LDS (fixed order, deterministic)
    #pragma unroll
    for (int c = 0; c < NCLS; ++c) {
        float v = ps[c];
        #pragma unroll
        for (int off = 32; off > 0; off >>= 1) v += __shfl_down(v, off, 64);
        if (lane == 0) s2w[wid][c] = v;
    }
    __syncthreads();

    // write private u16 partials, transposed: part[((b*NCLS+c)*BPB + chunk)*NB + bin]
    for (int i = tid; i < NCLS * NB; i += BLK1) {
        unsigned v = 0;
        #pragma unroll
        for (int k = 0; k < HCOPY; ++k) v += hist[k * HSTR + i];
        const int c = i >> 6, bin = i & (NB - 1);
        hist_part[((size_t)(b * NCLS + c) * BPB + chunk) * NB + bin] = (unsigned short)v;
    }
    if (tid < NCLS) {
        float v = 0.0f;
        #pragma unroll
        for (int w = 0; w < BLK1 / 64; ++w) v += s2w[w][tid];
        s2_part[(size_t)(b * NCLS + tid) * BPB + chunk] = v;
    }
}

// ---------------- Kernel 2: per (b,c): sum the BPB coalesced partials, wave
// suffix-scan, loss_bc = M/N + sum_k (dx/2)*(g(S_k)+g(S_{k+1})) + S2/N,
// g(r) = r/(n_c + r), n_c = NPIX - M, M = histogram total (bin 0 included).
__global__ __launch_bounds__(256) void k_finish(
    const unsigned short* __restrict__ hist_part, const float* __restrict__ s2_part,
    float* __restrict__ loss_bc)
{
    __shared__ unsigned hsum[4][NB];
    __shared__ float s2tot;

    const int bc   = blockIdx.x;
    const int tid  = threadIdx.x;
    const int lane = tid & 63;
    const int w    = tid >> 6;

    const unsigned short* hp = hist_part + (size_t)bc * BPB * NB;
    unsigned h = 0;
    #pragma unroll 1
    for (int k = 0; k < BPB / 4; ++k)
        h += hp[(size_t)(w * (BPB / 4) + k) * NB + lane];
    hsum[w][lane] = h;

    if (w == 1) {
        float v = 0.f;
        for (int k = lane; k < BPB; k += 64) v += s2_part[(size_t)bc * BPB + k];
        #pragma unroll
        for (int off = 32; off > 0; off >>= 1) v += __shfl_down(v, off, 64);
        if (lane == 0) s2tot = v;
    }
    __syncthreads();

    if (w == 0) {
        const unsigned hb = hsum[0][lane] + hsum[1][lane] + hsum[2][lane] + hsum[3][lane];
        // lane l takes bin 63-l: lane prefix-scan == bin suffix-scan
        const unsigned hrev = __shfl(hb, 63 - lane, 64);
        unsigned sc = hrev;
        #pragma unroll
        for (int off = 1; off < 64; off <<= 1) {
            const unsigned v = __shfl_up(sc, off, 64);
            if (lane >= off) sc += v;
        }
        const unsigned M   = __shfl(sc, 63, 64);     // total non-target count
        const float    ncf = (float)(NPIX - M);      // n_c
        const unsigned Rh  = sc;                     // inclusive suffix count
        const unsigned Rab = sc - hrev;              // strictly-above count

        const float gR  = (Rab > 0) ? (float)Rab / ((float)Rab + ncf) : 0.0f;
        const float gRh = (Rh  > 0) ? (float)Rh  / ((float)Rh  + ncf) : 0.0f;

        float red = gR + gRh;
        #pragma unroll
        for (int off = 32; off > 0; off >>= 1) red += __shfl_down(red, off, 64);
        if (lane == 0) {
            const float Nf = (float)NPIX;
            loss_bc[bc] = (float)M / Nf + red * (0.5f / (float)NB) + s2tot / Nf;
        }
    }
}

// ---------------- Kernel 3: deterministic tree-sum of the 152 per-(b,c) losses.
__global__ __launch_bounds__(256) void k_reduce(
    const float* __restrict__ loss_bc, float* __restrict__ out)
{
    __shared__ float r[256];
    const int tid = threadIdx.x;
    r[tid] = (tid < BATCH * NCLS) ? loss_bc[tid] : 0.0f;
    __syncthreads();
    for (int off = 128; off > 0; off >>= 1) {
        if (tid < off) r[tid] += r[tid + off];
        __syncthreads();
    }
    if (tid == 0) out[0] = r[0] * (1.0f / (float)(BATCH * NCLS));
}

extern "C" void kernel_launch(void* const* d_in, const int* in_sizes, int n_in,
                              void* d_out, int out_size, void* d_ws, size_t ws_size,
                              hipStream_t stream)
{
    const float* pred   = (const float*)d_in[0];
    const int*   target = (const int*)d_in[1];
    float*       out    = (float*)d_out;
    unsigned char* ws   = (unsigned char*)d_ws;

    unsigned short* hist_part = (unsigned short*)ws;   // 8*19*64*64 u16 = 1.25 MB
    float* s2_part = (float*)(ws + (size_t)BATCH * NCLS * BPB * NB * sizeof(unsigned short));
    float* loss_bc = (float*)((unsigned char*)s2_part + (size_t)BATCH * NCLS * BPB * sizeof(float));

    const dim3 g(BATCH * BPB), blk(BLK1);
    // ---- ablation probes (NPASS=3; outputs overwritten by the real V0 below) ----
    hipLaunchKernelGGL((k_hist<1, 3>), g, blk, 0, stream, pred, target, hist_part, s2_part);
    hipLaunchKernelGGL((k_hist<2, 3>), g, blk, 0, stream, pred, target, hist_part, s2_part);
    hipLaunchKernelGGL((k_hist<3, 3>), g, blk, 0, stream, pred, target, hist_part, s2_part);
    // ---- real kernel (NPASS=1) ----
    hipLaunchKernelGGL((k_hist<0, 1>), g, blk, 0, stream, pred, target, hist_part, s2_part);

    hipLaunchKernelGGL(k_finish, dim3(BATCH * NCLS), dim3(256), 0, stream,
                       hist_part, s2_part, loss_bc);
    hipLaunchKernelGGL(k_reduce, dim3(1), dim3(256), 0, stream, loss_bc, out);
}